// Round 2
// baseline (648.620 us; speedup 1.0000x reference)
//
#include <hip/hip_runtime.h>
#include <stdint.h>
#include <stddef.h>

#define BATCH 32768
#define HDIM  1024
#define NFAM  10

typedef short bf16x8 __attribute__((ext_vector_type(8)));
typedef float f32x4  __attribute__((ext_vector_type(4)));

// fp32 -> bf16 round-to-nearest-even
__device__ __forceinline__ unsigned short f2bf(float x) {
  unsigned int u = __builtin_bit_cast(unsigned int, x);
  u += 0x7fffu + ((u >> 16) & 1u);
  return (unsigned short)(u >> 16);
}

// async global->LDS, 16B per lane. LDS dest must be wave-uniform base + lane*16.
__device__ __forceinline__ void async_cp16(unsigned short* lds_dst, const unsigned short* g_src) {
  __builtin_amdgcn_global_load_lds(
      (const __attribute__((address_space(1))) unsigned int*)g_src,
      (__attribute__((address_space(3))) unsigned int*)lds_dst,
      16, 0, 0);
}

// ---------------------------------------------------------------------------
// Transpose + cast: in f32 [R][C] row-major -> out bf16 [C][R]
// ---------------------------------------------------------------------------
__global__ __launch_bounds__(256) void transpose_cast(
    const float* __restrict__ in, unsigned short* __restrict__ out, int R, int C) {
  __shared__ float tile[64][65];
  const int t = threadIdx.x;
  const int c = t & 63;
  const int r0 = t >> 6;
  const int rbase = blockIdx.y * 64, cbase = blockIdx.x * 64;
#pragma unroll
  for (int i = 0; i < 16; ++i) {
    int r = r0 + i * 4;
    tile[r][c] = in[(size_t)(rbase + r) * C + cbase + c];
  }
  __syncthreads();
#pragma unroll
  for (int i = 0; i < 16; ++i) {
    int r = r0 + i * 4;
    out[(size_t)(cbase + r) * R + rbase + c] = f2bf(tile[c][r]);
  }
}

// ---------------------------------------------------------------------------
// Prototype prep: bf16 copy + squared norms. One block per family.
// ---------------------------------------------------------------------------
__global__ __launch_bounds__(256) void proto_prep(
    const float* __restrict__ protos, unsigned short* __restrict__ protosB,
    float* __restrict__ p2) {
  __shared__ float red[4];
  const int j = blockIdx.x, t = threadIdx.x;
  float4 v = ((const float4*)(protos + (size_t)j * HDIM))[t];
  uint2 pk;
  pk.x = (unsigned)f2bf(v.x) | ((unsigned)f2bf(v.y) << 16);
  pk.y = (unsigned)f2bf(v.z) | ((unsigned)f2bf(v.w) << 16);
  *(uint2*)(protosB + (size_t)j * HDIM + t * 4) = pk;
  float s = v.x * v.x + v.y * v.y + v.z * v.z + v.w * v.w;
#pragma unroll
  for (int o = 32; o > 0; o >>= 1) s += __shfl_down(s, o);
  if ((t & 63) == 0) red[t >> 6] = s;
  __syncthreads();
  if (t == 0) p2[j] = red[0] + red[1] + red[2] + red[3];
}

// ---------------------------------------------------------------------------
// Nearest prototype + features->bf16 cast.
// Protos cached in LDS (40 KB). 16 rows/block: 4 waves x 4 rows sequential.
// ---------------------------------------------------------------------------
__global__ __launch_bounds__(256) void nearest_kernel(
    const float* __restrict__ feats, const float* __restrict__ protos,
    const float* __restrict__ p2, unsigned short* __restrict__ featsB,
    int* __restrict__ idx) {
  __shared__ float pl[NFAM * HDIM];  // fp32 protos, 40 KB
  const int t = threadIdx.x;
#pragma unroll
  for (int j = 0; j < NFAM; ++j)
    ((float4*)pl)[t + 256 * j] = ((const float4*)protos)[t + 256 * j];
  __syncthreads();

  const int wave = t >> 6, lane = t & 63;
  float P2[NFAM];
#pragma unroll
  for (int j = 0; j < NFAM; ++j) P2[j] = p2[j];

#pragma unroll
  for (int rr = 0; rr < 4; ++rr) {
    const int row = blockIdx.x * 16 + wave * 4 + rr;
    const float* f = feats + (size_t)row * HDIM;

    float dot[NFAM];
#pragma unroll
    for (int j = 0; j < NFAM; ++j) dot[j] = 0.f;
    float f2 = 0.f;

#pragma unroll
    for (int ch = 0; ch < 4; ++ch) {
      const int k4 = ch * 64 + lane;  // float4 index within row
      float4 v = ((const float4*)f)[k4];
      f2 += v.x * v.x + v.y * v.y + v.z * v.z + v.w * v.w;
#pragma unroll
      for (int j = 0; j < NFAM; ++j) {
        float4 p = ((const float4*)pl)[j * 256 + k4];
        dot[j] += v.x * p.x + v.y * p.y + v.z * p.z + v.w * p.w;
      }
      uint2 pk;
      pk.x = (unsigned)f2bf(v.x) | ((unsigned)f2bf(v.y) << 16);
      pk.y = (unsigned)f2bf(v.z) | ((unsigned)f2bf(v.w) << 16);
      *(uint2*)(featsB + (size_t)row * HDIM + k4 * 4) = pk;
    }

#pragma unroll
    for (int o = 32; o > 0; o >>= 1) {
      f2 += __shfl_down(f2, o);
#pragma unroll
      for (int j = 0; j < NFAM; ++j) dot[j] += __shfl_down(dot[j], o);
    }
    if (lane == 0) {
      int best = 0;
      float bd = f2 + P2[0] - 2.f * dot[0];
#pragma unroll
      for (int j = 1; j < NFAM; ++j) {
        float d = f2 + P2[j] - 2.f * dot[j];
        if (d < bd) { bd = d; best = j; }
      }
      idx[row] = best;
    }
  }
}

// ---------------------------------------------------------------------------
// bf16 GEMM, AITER-style: A staged via LDS (BK=64, two 32-k sub-buffers,
// reused 2x by waves), B loaded global->register (W panels are L2-resident).
// 128x128 tile, 4 waves as 2x2 of 64x64, 16x16x32 MFMA.
// XCD swizzle: row%8 -> XCD; a row-panel's 8 col-blocks consecutive per XCD.
// ---------------------------------------------------------------------------
template <int K, int GATHER, int RELU_BF16>
__global__ __launch_bounds__(256, 3) void gemm_kernel(
    const unsigned short* __restrict__ A,   // [M][1024] bf16
    const unsigned short* __restrict__ P,   // [NFAM][1024] bf16 (GATHER)
    const int* __restrict__ idx,            // [M] (GATHER)
    const unsigned short* __restrict__ Bt,  // [1024][K] bf16, n-major
    const float* __restrict__ bias,         // [1024]
    unsigned short* __restrict__ outB,      // [M][1024] bf16
    float* __restrict__ outF) {             // [M][1024] f32
  __shared__ unsigned short ldsA[2][128 * 32];  // two 32-k sub-buffers, 64B rows
  __shared__ int idxLds[128];

  const int t    = threadIdx.x;
  const int lane = t & 63;
  const int wid  = t >> 6;
  const int quad = lane >> 4;
  const int r16  = lane & 15;

  // swizzled block decode: b = slot*8 + xcd; row = (slot>>3)*8 + xcd; col = slot&7
  const int b = blockIdx.x;
  const int rowBase = (((b >> 3) >> 3) * 8 + (b & 7)) * 128;
  const int colBase = ((b >> 3) & 7) * 128;
  const int wm = (wid >> 1) * 64;
  const int wn = (wid & 1) * 64;

  if (GATHER) {
    if (t < 128) idxLds[t] = idx[rowBase + t];
    __syncthreads();
  }

  f32x4 acc[4][4];
#pragma unroll
  for (int i = 0; i < 4; ++i)
#pragma unroll
    for (int j = 0; j < 4; ++j) acc[i][j] = (f32x4){0.f, 0.f, 0.f, 0.f};

  // per-lane B base: row (n) = colBase + wn + r16, k-contiguous
  const unsigned short* bB = Bt + (size_t)(colBase + wn + r16) * K;

  // A staging: per sub-buffer s, chunk c in [0,512): row=c>>2, 16B piece=c&3
  const int rA0 = t >> 2,         pA0 = t & 3;
  const int rA1 = (t + 256) >> 2, pA1 = (t + 256) & 3;

  for (int kb = 0; kb < K; kb += 64) {
#pragma unroll
    for (int s = 0; s < 2; ++s) {
      const int k0 = kb + s * 32;
      const unsigned short *s0, *s1;
      if (!GATHER || kb < 1024) {
        s0 = A + (size_t)(rowBase + rA0) * 1024 + k0 + pA0 * 8;
        s1 = A + (size_t)(rowBase + rA1) * 1024 + k0 + pA1 * 8;
      } else {
        s0 = P + (size_t)idxLds[rA0] * 1024 + (k0 - 1024) + pA0 * 8;
        s1 = P + (size_t)idxLds[rA1] * 1024 + (k0 - 1024) + pA1 * 8;
      }
      async_cp16(&ldsA[s][t * 8], s0);
      async_cp16(&ldsA[s][(t + 256) * 8], s1);
    }
    __syncthreads();

    // B fragments for both sub-ks: global->reg (L1/L2-resident panel)
    bf16x8 bf0[4], bf1[4];
#pragma unroll
    for (int ni = 0; ni < 4; ++ni) {
      bf0[ni] = *(const bf16x8*)(bB + (size_t)ni * 16 * K + kb + quad * 8);
      bf1[ni] = *(const bf16x8*)(bB + (size_t)ni * 16 * K + kb + 32 + quad * 8);
    }
    bf16x8 a0[4], a1[4];
#pragma unroll
    for (int mi = 0; mi < 4; ++mi)
      a0[mi] = *(const bf16x8*)(&ldsA[0][(wm + mi * 16 + r16) * 32 + quad * 8]);
#pragma unroll
    for (int mi = 0; mi < 4; ++mi)
#pragma unroll
      for (int ni = 0; ni < 4; ++ni)
        acc[mi][ni] = __builtin_amdgcn_mfma_f32_16x16x32_bf16(a0[mi], bf0[ni], acc[mi][ni], 0, 0, 0);
#pragma unroll
    for (int mi = 0; mi < 4; ++mi)
      a1[mi] = *(const bf16x8*)(&ldsA[1][(wm + mi * 16 + r16) * 32 + quad * 8]);
#pragma unroll
    for (int mi = 0; mi < 4; ++mi)
#pragma unroll
      for (int ni = 0; ni < 4; ++ni)
        acc[mi][ni] = __builtin_amdgcn_mfma_f32_16x16x32_bf16(a1[mi], bf1[ni], acc[mi][ni], 0, 0, 0);
    __syncthreads();
  }

  // epilogue: C/D layout col=lane&15, row=quad*4+reg  [m89/m91]
#pragma unroll
  for (int mi = 0; mi < 4; ++mi) {
#pragma unroll
    for (int ni = 0; ni < 4; ++ni) {
      const int grow0 = rowBase + wm + mi * 16 + quad * 4;
      const int gcol  = colBase + wn + ni * 16 + r16;
      const float bv = bias[gcol];
#pragma unroll
      for (int r = 0; r < 4; ++r) {
        float v = acc[mi][ni][r] + bv;
        if (RELU_BF16) {
          v = fmaxf(v, 0.0f);
          outB[(size_t)(grow0 + r) * 1024 + gcol] = f2bf(v);
        } else {
          outF[(size_t)(grow0 + r) * 1024 + gcol] = v;
        }
      }
    }
  }
}

// ---------------------------------------------------------------------------
// Workspace layout unchanged (~140.7 MB)
// ---------------------------------------------------------------------------
extern "C" void kernel_launch(void* const* d_in, const int* in_sizes, int n_in,
                              void* d_out, int out_size, void* d_ws, size_t ws_size,
                              hipStream_t stream) {
  const float* feats  = (const float*)d_in[0];
  const float* protos = (const float*)d_in[1];
  const float* W1     = (const float*)d_in[2];
  const float* b1     = (const float*)d_in[3];
  const float* W2     = (const float*)d_in[4];
  const float* b2     = (const float*)d_in[5];
  float* out = (float*)d_out;

  unsigned short* featsB  = (unsigned short*)d_ws;
  unsigned short* hiddenB = featsB + (size_t)BATCH * HDIM;
  unsigned short* W1t     = hiddenB + (size_t)BATCH * HDIM;
  unsigned short* W2t     = W1t + (size_t)2 * HDIM * HDIM;
  unsigned short* protosB = W2t + (size_t)HDIM * HDIM;
  float* p2 = (float*)(protosB + NFAM * HDIM);
  int* idx  = (int*)(p2 + NFAM + 2);

  transpose_cast<<<dim3(HDIM / 64, 2 * HDIM / 64), 256, 0, stream>>>(W1, W1t, 2 * HDIM, HDIM);
  transpose_cast<<<dim3(HDIM / 64, HDIM / 64), 256, 0, stream>>>(W2, W2t, HDIM, HDIM);
  proto_prep<<<NFAM, 256, 0, stream>>>(protos, protosB, p2);
  nearest_kernel<<<BATCH / 16, 256, 0, stream>>>(feats, protos, p2, featsB, idx);
  // GEMM1: hidden = relu([feats | proto[idx]] @ W1 + b1)   K=2048
  gemm_kernel<2048, 1, 1><<<2048, 256, 0, stream>>>(
      featsB, protosB, idx, W1t, b1, hiddenB, nullptr);
  // GEMM2: out = hidden @ W2 + b2                          K=1024
  gemm_kernel<1024, 0, 0><<<2048, 256, 0, stream>>>(
      hiddenB, nullptr, nullptr, W2t, b2, nullptr, out);
}

// Round 3
// 449.596 us; speedup vs baseline: 1.4427x; 1.4427x over previous
//
#include <hip/hip_runtime.h>
#include <stdint.h>
#include <stddef.h>

#define BATCH 32768
#define HDIM  1024
#define NFAM  10

typedef short bf16x8 __attribute__((ext_vector_type(8)));
typedef float f32x4  __attribute__((ext_vector_type(4)));

// fp32 -> bf16 round-to-nearest-even
__device__ __forceinline__ unsigned short f2bf(float x) {
  unsigned int u = __builtin_bit_cast(unsigned int, x);
  u += 0x7fffu + ((u >> 16) & 1u);
  return (unsigned short)(u >> 16);
}

// async global->LDS, 16B per lane. LDS dest must be wave-uniform base + lane*16.
__device__ __forceinline__ void async_cp16(unsigned short* lds_dst, const unsigned short* g_src) {
  __builtin_amdgcn_global_load_lds(
      (const __attribute__((address_space(1))) unsigned int*)g_src,
      (__attribute__((address_space(3))) unsigned int*)lds_dst,
      16, 0, 0);
}

// ---------------------------------------------------------------------------
// Transpose + cast: in f32 [R][C] row-major -> out bf16 [C][R]
// ---------------------------------------------------------------------------
__global__ __launch_bounds__(256) void transpose_cast(
    const float* __restrict__ in, unsigned short* __restrict__ out, int R, int C) {
  __shared__ float tile[64][65];
  const int t = threadIdx.x;
  const int c = t & 63;
  const int r0 = t >> 6;
  const int rbase = blockIdx.y * 64, cbase = blockIdx.x * 64;
#pragma unroll
  for (int i = 0; i < 16; ++i) {
    int r = r0 + i * 4;
    tile[r][c] = in[(size_t)(rbase + r) * C + cbase + c];
  }
  __syncthreads();
#pragma unroll
  for (int i = 0; i < 16; ++i) {
    int r = r0 + i * 4;
    out[(size_t)(cbase + r) * R + rbase + c] = f2bf(tile[c][r]);
  }
}

// ---------------------------------------------------------------------------
// Prototype prep: bf16 copy + squared norms. One block per family.
// ---------------------------------------------------------------------------
__global__ __launch_bounds__(256) void proto_prep(
    const float* __restrict__ protos, unsigned short* __restrict__ protosB,
    float* __restrict__ p2) {
  __shared__ float red[4];
  const int j = blockIdx.x, t = threadIdx.x;
  float4 v = ((const float4*)(protos + (size_t)j * HDIM))[t];
  uint2 pk;
  pk.x = (unsigned)f2bf(v.x) | ((unsigned)f2bf(v.y) << 16);
  pk.y = (unsigned)f2bf(v.z) | ((unsigned)f2bf(v.w) << 16);
  *(uint2*)(protosB + (size_t)j * HDIM + t * 4) = pk;
  float s = v.x * v.x + v.y * v.y + v.z * v.z + v.w * v.w;
#pragma unroll
  for (int o = 32; o > 0; o >>= 1) s += __shfl_down(s, o);
  if ((t & 63) == 0) red[t >> 6] = s;
  __syncthreads();
  if (t == 0) p2[j] = red[0] + red[1] + red[2] + red[3];
}

// ---------------------------------------------------------------------------
// Nearest prototype + features->bf16 cast.
// Protos cached in LDS (40 KB). 16 rows/block: 4 waves x 4 rows sequential.
// ---------------------------------------------------------------------------
__global__ __launch_bounds__(256) void nearest_kernel(
    const float* __restrict__ feats, const float* __restrict__ protos,
    const float* __restrict__ p2, unsigned short* __restrict__ featsB,
    int* __restrict__ idx) {
  __shared__ float pl[NFAM * HDIM];  // fp32 protos, 40 KB
  const int t = threadIdx.x;
#pragma unroll
  for (int j = 0; j < NFAM; ++j)
    ((float4*)pl)[t + 256 * j] = ((const float4*)protos)[t + 256 * j];
  __syncthreads();

  const int wave = t >> 6, lane = t & 63;
  float P2[NFAM];
#pragma unroll
  for (int j = 0; j < NFAM; ++j) P2[j] = p2[j];

#pragma unroll
  for (int rr = 0; rr < 4; ++rr) {
    const int row = blockIdx.x * 16 + wave * 4 + rr;
    const float* f = feats + (size_t)row * HDIM;

    float dot[NFAM];
#pragma unroll
    for (int j = 0; j < NFAM; ++j) dot[j] = 0.f;
    float f2 = 0.f;

#pragma unroll
    for (int ch = 0; ch < 4; ++ch) {
      const int k4 = ch * 64 + lane;  // float4 index within row
      float4 v = ((const float4*)f)[k4];
      f2 += v.x * v.x + v.y * v.y + v.z * v.z + v.w * v.w;
#pragma unroll
      for (int j = 0; j < NFAM; ++j) {
        float4 p = ((const float4*)pl)[j * 256 + k4];
        dot[j] += v.x * p.x + v.y * p.y + v.z * p.z + v.w * p.w;
      }
      uint2 pk;
      pk.x = (unsigned)f2bf(v.x) | ((unsigned)f2bf(v.y) << 16);
      pk.y = (unsigned)f2bf(v.z) | ((unsigned)f2bf(v.w) << 16);
      *(uint2*)(featsB + (size_t)row * HDIM + k4 * 4) = pk;
    }

#pragma unroll
    for (int o = 32; o > 0; o >>= 1) {
      f2 += __shfl_down(f2, o);
#pragma unroll
      for (int j = 0; j < NFAM; ++j) dot[j] += __shfl_down(dot[j], o);
    }
    if (lane == 0) {
      int best = 0;
      float bd = f2 + P2[0] - 2.f * dot[0];
#pragma unroll
      for (int j = 1; j < NFAM; ++j) {
        float d = f2 + P2[j] - 2.f * dot[j];
        if (d < bd) { bd = d; best = j; }
      }
      idx[row] = best;
    }
  }
}

// ---------------------------------------------------------------------------
// bf16 GEMM: A and B staged via global_load_lds. BK=64 (two 32-k sub-buffers
// per operand -> half the barrier drains of BK=32). XOR source-swizzle:
// LDS slot (row, p) holds global 16B-piece p ^ ((row>>1)&3), so ds_read_b128
// readers spread 16 lanes over all 8 four-bank slots (2-way = free, m136).
// 128x128 tile, 4 waves as 2x2 of 64x64, 16x16x32 MFMA.
// XCD swizzle: b&7 -> XCD; each XCD sweeps all 8 col-blocks of a row-panel
// so the B panel stays L2/L3-resident (R2: FETCH ~= A only).
// ---------------------------------------------------------------------------
template <int K, int GATHER, int RELU_BF16>
__global__ __launch_bounds__(256) void gemm_kernel(
    const unsigned short* __restrict__ A,   // [M][1024] bf16
    const unsigned short* __restrict__ P,   // [NFAM][1024] bf16 (GATHER)
    const int* __restrict__ idx,            // [M] (GATHER)
    const unsigned short* __restrict__ Bt,  // [1024][K] bf16, n-major
    const float* __restrict__ bias,         // [1024]
    unsigned short* __restrict__ outB,      // [M][1024] bf16
    float* __restrict__ outF) {             // [M][1024] f32
  __shared__ unsigned short ldsA[2][128 * 32];  // [sub][row*32 + piece*8]
  __shared__ unsigned short ldsB[2][128 * 32];
  __shared__ int idxLds[128];

  const int t    = threadIdx.x;
  const int lane = t & 63;
  const int wid  = t >> 6;
  const int quad = lane >> 4;
  const int r16  = lane & 15;

  // swizzled block decode: col = (b>>3)&7, row = (b>>6)*8 + (b&7)
  const int b = blockIdx.x;
  const int rowBase = ((b >> 6) * 8 + (b & 7)) * 128;
  const int colBase = ((b >> 3) & 7) * 128;
  const int wm = (wid >> 1) * 64;
  const int wn = (wid & 1) * 64;

  if (GATHER) {
    if (t < 128) idxLds[t] = idx[rowBase + t];
    __syncthreads();
  }

  f32x4 acc[4][4];
#pragma unroll
  for (int i = 0; i < 4; ++i)
#pragma unroll
    for (int j = 0; j < 4; ++j) acc[i][j] = (f32x4){0.f, 0.f, 0.f, 0.f};

  // staging: thread t handles rows r0 = t>>2 and r1 = r0+64, piece p = t&3.
  // swizzled global piece q = p ^ ((row>>1)&3); identical for r0 and r1
  // since they differ by 64 (64>>1 = 32 ≡ 0 mod 4).
  const int r0 = t >> 2, r1 = r0 + 64;
  const int q = (t & 3) ^ ((t >> 3) & 3);
  const unsigned short* bB0 = Bt + (size_t)(colBase + r0) * K + q * 8;
  const unsigned short* bB1 = Bt + (size_t)(colBase + r1) * K + q * 8;

  // reader piece (per-lane constant): global quad lives at LDS piece
  // quad ^ ((r16>>1)&3)  (wm/wn/mi*16 are ≡0 mod 8 after >>1, mod 4)
  const int pr = quad ^ ((r16 >> 1) & 3);

  for (int kb = 0; kb < K; kb += 64) {
    const unsigned short *aBase0, *aBase1;
    int koff;
    if (!GATHER || kb < 1024) {
      aBase0 = A + (size_t)(rowBase + r0) * 1024 + q * 8;
      aBase1 = A + (size_t)(rowBase + r1) * 1024 + q * 8;
      koff = kb;
    } else {
      aBase0 = P + (size_t)idxLds[r0] * 1024 + q * 8;
      aBase1 = P + (size_t)idxLds[r1] * 1024 + q * 8;
      koff = kb - 1024;
    }
#pragma unroll
    for (int s = 0; s < 2; ++s) {
      async_cp16(&ldsA[s][t * 8],         aBase0 + koff + s * 32);
      async_cp16(&ldsA[s][(t + 256) * 8], aBase1 + koff + s * 32);
      async_cp16(&ldsB[s][t * 8],         bB0 + kb + s * 32);
      async_cp16(&ldsB[s][(t + 256) * 8], bB1 + kb + s * 32);
    }
    __syncthreads();

#pragma unroll
    for (int s = 0; s < 2; ++s) {
      bf16x8 af[4], bfr[4];
#pragma unroll
      for (int mi = 0; mi < 4; ++mi)
        af[mi] = *(const bf16x8*)(&ldsA[s][(wm + mi * 16 + r16) * 32 + pr * 8]);
#pragma unroll
      for (int ni = 0; ni < 4; ++ni)
        bfr[ni] = *(const bf16x8*)(&ldsB[s][(wn + ni * 16 + r16) * 32 + pr * 8]);
#pragma unroll
      for (int mi = 0; mi < 4; ++mi)
#pragma unroll
        for (int ni = 0; ni < 4; ++ni)
          acc[mi][ni] = __builtin_amdgcn_mfma_f32_16x16x32_bf16(af[mi], bfr[ni], acc[mi][ni], 0, 0, 0);
    }
    __syncthreads();
  }

  // epilogue: C/D layout col=lane&15, row=quad*4+reg  [m89/m91]
#pragma unroll
  for (int mi = 0; mi < 4; ++mi) {
#pragma unroll
    for (int ni = 0; ni < 4; ++ni) {
      const int grow0 = rowBase + wm + mi * 16 + quad * 4;
      const int gcol  = colBase + wn + ni * 16 + r16;
      const float bv = bias[gcol];
#pragma unroll
      for (int r = 0; r < 4; ++r) {
        float v = acc[mi][ni][r] + bv;
        if (RELU_BF16) {
          v = fmaxf(v, 0.0f);
          outB[(size_t)(grow0 + r) * 1024 + gcol] = f2bf(v);
        } else {
          outF[(size_t)(grow0 + r) * 1024 + gcol] = v;
        }
      }
    }
  }
}

// ---------------------------------------------------------------------------
// Workspace layout (~140.7 MB): featsB | hiddenB | W1t | W2t | protosB | p2 | idx
// ---------------------------------------------------------------------------
extern "C" void kernel_launch(void* const* d_in, const int* in_sizes, int n_in,
                              void* d_out, int out_size, void* d_ws, size_t ws_size,
                              hipStream_t stream) {
  const float* feats  = (const float*)d_in[0];
  const float* protos = (const float*)d_in[1];
  const float* W1     = (const float*)d_in[2];
  const float* b1     = (const float*)d_in[3];
  const float* W2     = (const float*)d_in[4];
  const float* b2     = (const float*)d_in[5];
  float* out = (float*)d_out;

  unsigned short* featsB  = (unsigned short*)d_ws;
  unsigned short* hiddenB = featsB + (size_t)BATCH * HDIM;
  unsigned short* W1t     = hiddenB + (size_t)BATCH * HDIM;
  unsigned short* W2t     = W1t + (size_t)2 * HDIM * HDIM;
  unsigned short* protosB = W2t + (size_t)HDIM * HDIM;
  float* p2 = (float*)(protosB + NFAM * HDIM);
  int* idx  = (int*)(p2 + NFAM + 2);

  transpose_cast<<<dim3(HDIM / 64, 2 * HDIM / 64), 256, 0, stream>>>(W1, W1t, 2 * HDIM, HDIM);
  transpose_cast<<<dim3(HDIM / 64, HDIM / 64), 256, 0, stream>>>(W2, W2t, HDIM, HDIM);
  proto_prep<<<NFAM, 256, 0, stream>>>(protos, protosB, p2);
  nearest_kernel<<<BATCH / 16, 256, 0, stream>>>(feats, protos, p2, featsB, idx);
  // GEMM1: hidden = relu([feats | proto[idx]] @ W1 + b1)   K=2048
  gemm_kernel<2048, 1, 1><<<2048, 256, 0, stream>>>(
      featsB, protosB, idx, W1t, b1, hiddenB, nullptr);
  // GEMM2: out = hidden @ W2 + b2                          K=1024
  gemm_kernel<1024, 0, 0><<<2048, 256, 0, stream>>>(
      hiddenB, nullptr, nullptr, W2t, b2, nullptr, out);
}